// Round 4
// baseline (438.582 us; speedup 1.0000x reference)
//
#include <hip/hip_runtime.h>
#include <math.h>

#define B_    128
#define CIN   128
#define TIN   2500
#define COUT  64
#define KW    27
#define TOUT  625
#define TPAD  640   // padded t extent for bf16 q/k/v planes
#define CTT   16    // conv t-tile (16 -> 22.7KB LDS -> 7 blocks/CU)
#define GR2   88    // conv staging rows (span 4*15+27=87, pad to 88)

typedef __bf16 bf16x8 __attribute__((ext_vector_type(8)));
typedef float  f32x4  __attribute__((ext_vector_type(4)));

__device__ __forceinline__ unsigned short f32_to_bf16_rne(float v) {
    unsigned u = __float_as_uint(v);
    u += 0x7FFFu + ((u >> 16) & 1u);
    return (unsigned short)(u >> 16);
}

__device__ __forceinline__ f32x4 mfma_bf16(bf16x8 a, bf16x8 b, f32x4 c) {
    return __builtin_amdgcn_mfma_f32_16x16x32_bf16(a, b, c, 0, 0, 0);
}

// ---------------------------------------------------------------------------
// K0: alpha[o] = mean|w|; packed sign bits:
//     sgn2[(kk*4+kg)*64 + o] = u32, byte cs holds bits j for c = cs*32+kg*8+j
// ---------------------------------------------------------------------------
__global__ void binarize_kernel(const float* __restrict__ w,
                                unsigned* __restrict__ sgn2,
                                float* __restrict__ alpha_out) {
    int o = blockIdx.x, tid = threadIdx.x;
    __shared__ float red[256];
    const float* wo_ = w + (size_t)o * (CIN * KW);
    float s = 0.f;
    for (int idx = tid; idx < CIN * KW; idx += 256) s += fabsf(wo_[idx]);
    red[tid] = s;
    __syncthreads();
    for (int st = 128; st > 0; st >>= 1) {
        if (tid < st) red[tid] += red[tid + st];
        __syncthreads();
    }
    if (tid == 0) alpha_out[o] = red[0] / (float)(CIN * KW);

    for (int t = tid; t < KW * 4; t += 256) {
        int kk = t >> 2, kg = t & 3;
        unsigned u = 0;
#pragma unroll
        for (int cs = 0; cs < 4; cs++) {
#pragma unroll
            for (int j = 0; j < 8; j++) {
                int c = cs * 32 + kg * 8 + j;
                float v = wo_[c * KW + kk];
                unsigned bit = (v > 0.f) ? 0u : 1u;
                u |= bit << (cs * 8 + j);
            }
        }
        sgn2[(kk * 4 + kg) * 64 + o] = u;
    }
}

// ---------------------------------------------------------------------------
// K0b: blocks 0-2: wq/wk/wv -> bf16 hi/lo planes [o][c] (native layout);
//      block 3: wo -> bf16 hi/lo [o][c]; block 4: fold alpha+bias+BN.
// ---------------------------------------------------------------------------
__global__ void transpose_w_kernel(const float* __restrict__ wq, const float* __restrict__ wk,
                                   const float* __restrict__ wv, const float* __restrict__ wo,
                                   const float* __restrict__ conv_b, const float* __restrict__ gamma_,
                                   const float* __restrict__ beta_, const float* __restrict__ mean_,
                                   const float* __restrict__ var_, const float* __restrict__ alpha_,
                                   unsigned short* __restrict__ w3_h, unsigned short* __restrict__ w3_l,
                                   unsigned short* __restrict__ wo_h, unsigned short* __restrict__ wo_l,
                                   float* __restrict__ scA, float* __restrict__ scB) {
    if (blockIdx.x < 3) {
        const float* srcs[3] = {wq, wk, wv};
        const float* src = srcs[blockIdx.x];
        unsigned short* dh = w3_h + (size_t)blockIdx.x * 4096;
        unsigned short* dl = w3_l + (size_t)blockIdx.x * 4096;
        for (int idx = threadIdx.x; idx < 4096; idx += 256) {
            float v = src[idx];
            unsigned short h = f32_to_bf16_rne(v);
            float hf = __uint_as_float((unsigned)h << 16);
            dh[idx] = h;
            dl[idx] = f32_to_bf16_rne(v - hf);
        }
    } else if (blockIdx.x == 3) {
        for (int idx = threadIdx.x; idx < 4096; idx += 256) {
            float v = wo[idx];
            unsigned short h = f32_to_bf16_rne(v);
            float hf = __uint_as_float((unsigned)h << 16);
            wo_h[idx] = h;
            wo_l[idx] = f32_to_bf16_rne(v - hf);
        }
    } else {
        int o = threadIdx.x;
        if (o < 64) {
            float inv = rsqrtf(var_[o] + 1e-5f);
            float G = gamma_[o] * inv;
            scA[o] = alpha_[o] * G;
            scB[o] = (conv_b[o] - mean_[o]) * G + beta_[o];
        }
    }
}

// ---------------------------------------------------------------------------
// K1: binarized conv1d via bf16 MFMA + BN/ELU -> y, fused q/k/v projections.
//   This round: 16-t tile (was 32) -> staging LDS 38.9->22.7 KB -> 7 blocks/CU
//   (occupancy cap 50%->87.5%; the kernel was latency-bound at 40%).
//   XCD swizzle: consecutive t-tiles of one b on the same XCD (shared x rows).
//   Overlays (y/s/q/k/v, 10 KB) sit inside the dead xhi buffer after the
//   K-loop barrier. Sign expansion via the 16-entry b64 LUT (conflict-free).
// ---------------------------------------------------------------------------
__global__ __launch_bounds__(256, 7) void conv_kernel(
    const float* __restrict__ x, const unsigned* __restrict__ sgn2,
    const float* __restrict__ scA, const float* __restrict__ scB,
    const unsigned short* __restrict__ w3_h, const unsigned short* __restrict__ w3_l,
    float* __restrict__ y_out,
    unsigned short* __restrict__ q_h, unsigned short* __restrict__ k_h,
    unsigned short* __restrict__ vT_h)
{
    __shared__ __align__(16) unsigned short xhi[GR2 * 128];    // 22528 B
    __shared__ __align__(16) unsigned long long sgnlut[16];    // 128 B
    // overlays on xhi (valid only after the post-K-loop barrier):
    unsigned short* y_sh = xhi;            // [16][64] bf16, c8-swizzled
    unsigned short* s_sh = xhi + 1024;     // spike plane, same layout
    unsigned short* q_sh = xhi + 2048;     // [16][64] bf16, o8-swizzled
    unsigned short* k_sh = xhi + 3072;
    unsigned short* v_sh = xhi + 4096;     // [64][16] bf16, linear

    int tid = threadIdx.x;
    // XCD-aware remap (5120 wgs, 5120%8==0 -> bijective): each XCD owns
    // 16 consecutive b, t-tiles of one b temporally adjacent.
    int id = blockIdx.x + 40 * blockIdx.y;
    int nid = (id & 7) * 640 + (id >> 3);
    int b = nid / 40;
    int t0 = (nid - b * 40) * CTT;

    // ---- nibble -> 4x bf16(+-1.0) LUT (bit=1 => -1.0) ----
    if (tid < 16) {
        unsigned long long e = 0;
#pragma unroll
        for (int j = 0; j < 4; ++j) {
            unsigned long long h = ((tid >> j) & 1) ? 0xBF80ull : 0x3F80ull;
            e |= h << (16 * j);
        }
        sgnlut[tid] = e;
    }

    // ---- stage x (hi bf16, RNE): task = (c8, gl); 8 loads -> one b128 ----
    const float* xb = x + (size_t)b * CIN * TIN;
    int gbase = 4 * t0 - 13;
    for (int task = tid; task < 16 * GR2; task += 256) {
        int c8 = task / GR2, gl = task - c8 * GR2;
        int g = gbase + gl;
        bool valid = (gl < 87) && ((unsigned)g < (unsigned)TIN);
        float vs[8];
#pragma unroll
        for (int j = 0; j < 8; j++)
            vs[j] = valid ? xb[(size_t)(c8 * 8 + j) * TIN + g] : 0.f;
        union { unsigned u[4]; uint4 q; } H;
#pragma unroll
        for (int j = 0; j < 4; j++) {
            unsigned short h0 = f32_to_bf16_rne(vs[2 * j]);
            unsigned short h1 = f32_to_bf16_rne(vs[2 * j + 1]);
            H.u[j] = (unsigned)h0 | ((unsigned)h1 << 16);
        }
        int c8p = c8 ^ ((gl >> 2) & 15);
        *(uint4*)(xhi + gl * 128 + c8p * 8) = H.q;
    }
    __syncthreads();

    // ---- MFMA K-loop: wave w = o slice [16w,16w+16) x 16 t ----
    int wave = tid >> 6, lane = tid & 63;
    int o0 = wave * 16;
    int n = lane & 15, kg = lane >> 4;

    f32x4 acc = {0.f, 0.f, 0.f, 0.f};
    const unsigned* sgb = sgn2 + (size_t)kg * 64 + o0 + n;
    unsigned sa = sgb[0];

#pragma unroll 1
    for (int kk = 0; kk < KW; ++kk) {
        unsigned na = 0;
        if (kk < KW - 1) na = sgb[(kk + 1) * 256];   // prefetch (L1-hot)
        int gl = 4 * n + kk;
        int rot = (gl >> 2) & 15;
        const unsigned short* xr0 = xhi + gl * 128;
#pragma unroll
        for (int cs = 0; cs < 4; ++cs) {
            int c8p = (cs * 4 + kg) ^ rot;
            bf16x8 b0 = *(const bf16x8*)(xr0 + c8p * 8);
            unsigned byte = (sa >> (8 * cs)) & 0xFFu;
            union { unsigned long long u[2]; bf16x8 v; } A;
            A.u[0] = sgnlut[byte & 15u];
            A.u[1] = sgnlut[byte >> 4];
            acc = mfma_bf16(A.v, b0, acc);
        }
        sa = na;
    }

    // ---- epilogue: BN/ELU, y_out store, pack y+spike (pads -> 0) ----
    int quad = kg, col = n;
    int t_g = t0 + col;
    unsigned long long ypk = 0, spk = 0;
#pragma unroll
    for (int r = 0; r < 4; ++r) {
        int o = o0 + quad * 4 + r;
        float s = acc[r] * scA[o] + scB[o];
        float yv = s > 0.f ? s : expm1f(s);
        if (t_g < TOUT) {
            y_out[((size_t)b * COUT + o) * TOUT + t_g] = yv;
            ypk |= (unsigned long long)f32_to_bf16_rne(yv) << (16 * r);
            if (yv > 0.f) spk |= 0x3F80ull << (16 * r);
        }
    }
    __syncthreads();     // all waves done reading xhi -> overlays valid

    int c8w = (o0 >> 3) + (quad >> 1);   // ((o0 + quad*4) >> 3)
    int cof = (quad & 1) * 4;
    int idxw = col * 64 + ((c8w ^ (col & 7)) << 3) + cof;
    *(unsigned long long*)(y_sh + idxw) = ypk;
    *(unsigned long long*)(s_sh + idxw) = spk;
    __syncthreads();

    // ---- fused projections: wave w -> o-rows [o0, o0+16) of q,k,v ----
    bf16x8 sf[2], yf[2];                 // [ks] B-fragments (c-halves)
#pragma unroll
    for (int ks = 0; ks < 2; ++ks) {
        int idx = col * 64 + (((ks * 4 + quad) ^ (col & 7)) << 3);
        sf[ks] = *(const bf16x8*)(s_sh + idx);
        yf[ks] = *(const bf16x8*)(y_sh + idx);
    }
    size_t wofs = (size_t)(o0 + col) * 64 + quad * 8;
    f32x4 qa = {0.f, 0.f, 0.f, 0.f};
    f32x4 ka = {0.f, 0.f, 0.f, 0.f};
    f32x4 va = {0.f, 0.f, 0.f, 0.f};
#pragma unroll
    for (int ks = 0; ks < 2; ++ks) {
        bf16x8 aqh = *(const bf16x8*)(w3_h + wofs + ks * 32);
        bf16x8 aql = *(const bf16x8*)(w3_l + wofs + ks * 32);
        bf16x8 akh = *(const bf16x8*)(w3_h + 4096 + wofs + ks * 32);
        bf16x8 akl = *(const bf16x8*)(w3_l + 4096 + wofs + ks * 32);
        bf16x8 avh = *(const bf16x8*)(w3_h + 8192 + wofs + ks * 32);
        bf16x8 avl = *(const bf16x8*)(w3_l + 8192 + wofs + ks * 32);
        qa = mfma_bf16(aqh, sf[ks], qa);
        qa = mfma_bf16(aql, sf[ks], qa);
        ka = mfma_bf16(akh, sf[ks], ka);
        ka = mfma_bf16(akl, sf[ks], ka);
        va = mfma_bf16(avh, yf[ks], va);
        va = mfma_bf16(avl, yf[ks], va);
    }
    // q/k -> LDS [t][o] (o8-swizzled, 8B packs); v -> v_sh [c][t] linear
    {
        unsigned long long qp = 0, kp = 0;
#pragma unroll
        for (int r = 0; r < 4; ++r) {
            qp |= (unsigned long long)f32_to_bf16_rne(qa[r]) << (16 * r);
            kp |= (unsigned long long)f32_to_bf16_rne(ka[r]) << (16 * r);
        }
        *(unsigned long long*)(q_sh + idxw) = qp;
        *(unsigned long long*)(k_sh + idxw) = kp;
#pragma unroll
        for (int r = 0; r < 4; ++r) {
            int c = o0 + quad * 4 + r;
            v_sh[c * 16 + col] = f32_to_bf16_rne(va[r]);
        }
    }
    __syncthreads();

    // ---- cooperative coalesced stores ----
    {
        int task = tid & 127;
        int tl = task >> 3, seg = task & 7;
        int idx = tl * 64 + ((seg ^ (tl & 7)) << 3);
        const unsigned short* srcp = (tid < 128) ? q_sh : k_sh;
        unsigned short* dstp = (tid < 128) ? q_h : k_h;
        uint4 val = *(const uint4*)(srcp + idx);
        *(uint4*)(dstp + ((size_t)b * TPAD + t0 + tl) * 64 + seg * 8) = val;
        if (tid < 128) {
            int c = tid >> 1, ts = tid & 1;
            uint4 vv = *(const uint4*)(v_sh + c * 16 + ts * 8);
            *(uint4*)(vT_h + ((size_t)b * 64 + c) * TPAD + t0 + ts * 8) = vv;
        }
    }
}

// ---------------------------------------------------------------------------
// K2: MFMA attention per (b, 16-t tile), 512 threads / 8 waves.
//   This round: XCD-aware block remap (5120%8==0, bijective) so all 40
//   t-tiles of one b run on one XCD -> K/V become L2-resident (~480KB live
//   per XCD << 4MB) instead of 8x-duplicated HBM fetches.
// ---------------------------------------------------------------------------
__global__ __launch_bounds__(512, 3) void attn_kernel(
    const unsigned short* __restrict__ q_h, const unsigned short* __restrict__ k_h,
    const unsigned short* __restrict__ vT_h, const float* __restrict__ y,
    const unsigned short* __restrict__ wo_h, const unsigned short* __restrict__ wo_l,
    float* __restrict__ out)
{
    __shared__ __align__(16) float sc_sh[16 * 648];  // 41472 B (f32 scores, then bf16 P in place)
    __shared__ float ctx_sh[2 * 64 * 17];  // 8704 B (kh partials)
    __shared__ float rden[16];             // 64 B  => 50240 total -> 3 blk/CU

    int tid = threadIdx.x;
    int id = blockIdx.x + 40 * blockIdx.y;
    int nid = (id & 7) * 640 + (id >> 3);
    int b = nid / 40;
    int t0 = (nid - b * 40) * 16;

    int wave = tid >> 6, lane = tid & 63;
    int quad = lane >> 4, nlo = lane & 15;

    // ---- scores: wave w covers s in [w*80, (w+1)*80), 5 nt steps ----
    const unsigned short* qb = q_h + ((size_t)b * TPAD + t0 + nlo) * 64 + quad * 8;
    bf16x8 qa0 = *(const bf16x8*)(qb);
    bf16x8 qa1 = *(const bf16x8*)(qb + 32);
    const unsigned short* kbase = k_h + (size_t)b * TPAD * 64 + quad * 8;
#pragma unroll 5
    for (int nt = 0; nt < 5; ++nt) {
        int s = wave * 80 + nt * 16 + nlo;
        const unsigned short* krow = kbase + (size_t)s * 64;
        bf16x8 kb0 = *(const bf16x8*)(krow);
        bf16x8 kb1 = *(const bf16x8*)(krow + 32);
        f32x4 acc = {0.f, 0.f, 0.f, 0.f};
        acc = mfma_bf16(qa0, kb0, acc);
        acc = mfma_bf16(qa1, kb1, acc);
#pragma unroll
        for (int r = 0; r < 4; ++r)
            sc_sh[(quad * 4 + r) * 648 + s] = acc[r] * 0.125f;
    }
    __syncthreads();

    // ---- softmax over s: 32 lanes/row, shfl reductions, in-place bf16 P ----
    int ti1 = tid >> 5, sg = tid & 31;
    float* srow = &sc_sh[ti1 * 648];
    float mx = -3.0e38f;
    for (int s = sg; s < TOUT; s += 32) mx = fmaxf(mx, srow[s]);
#pragma unroll
    for (int off = 16; off >= 1; off >>= 1) mx = fmaxf(mx, __shfl_xor(mx, off));

    unsigned short* prow = (unsigned short*)srow;   // row-local halves 0..1295
    float sum = 0.f;
#pragma unroll
    for (int k2 = 0; k2 < 10; ++k2) {
        int s = 2 * sg + 64 * k2;                   // even, covers 0..638
        float2 v2 = *(const float2*)(srow + s);     // ds_read_b64
        float e0 = (s     < TOUT) ? __expf(v2.x - mx) : 0.f;
        float e1 = (s + 1 < TOUT) ? __expf(v2.y - mx) : 0.f;
        sum += e0 + e1;
        unsigned u0 = __float_as_uint(e0); u0 += 0x7FFFu + ((u0 >> 16) & 1u);
        unsigned u1 = __float_as_uint(e1); u1 += 0x7FFFu + ((u1 >> 16) & 1u);
        *(unsigned*)(prow + s) = (u0 >> 16) | (u1 & 0xFFFF0000u);  // halves s, s+1
    }
#pragma unroll
    for (int off = 16; off >= 1; off >>= 1) sum += __shfl_xor(sum, off);
    if (sg == 0) rden[ti1] = 1.f / sum;
    __syncthreads();

    // ---- PV: wave -> (c-tile = (w&3)*16, K-half = w>>2); 10 ks steps ----
    int cw = (wave & 3) * 16, kh = wave >> 2;
    const unsigned short* vb = vT_h + ((size_t)b * 64 + cw + nlo) * TPAD;
    const unsigned short* pb = (const unsigned short*)sc_sh + nlo * 1296;  // P row t=nlo
    f32x4 cacc = {0.f, 0.f, 0.f, 0.f};
    int ks0 = kh * 10;
#pragma unroll 5
    for (int i = 0; i < 10; ++i) {
        int ks = ks0 + i;
        bf16x8 pv = *(const bf16x8*)(pb + ks * 32 + quad * 8);   // ds_read_b128
        bf16x8 v8 = *(const bf16x8*)(vb + ks * 32 + quad * 8);
        cacc = mfma_bf16(pv, v8, cacc);
    }
#pragma unroll
    for (int r = 0; r < 4; ++r)
        ctx_sh[kh * 1088 + (cw + nlo) * 17 + quad * 4 + r] = cacc[r] * rden[quad * 4 + r];
    __syncthreads();

    // ---- epilogue (waves 0-3): out = y + wo @ ctx, wave -> o-tile ----
    if (wave < 4) {
        const unsigned short* woh = wo_h + (size_t)(wave * 16 + nlo) * 64 + quad * 8;
        const unsigned short* wol = wo_l + (size_t)(wave * 16 + nlo) * 64 + quad * 8;
        f32x4 oacc = {0.f, 0.f, 0.f, 0.f};
#pragma unroll
        for (int ks = 0; ks < 2; ++ks) {
            union { unsigned short u[8]; bf16x8 v; } Bc;
#pragma unroll
            for (int j = 0; j < 8; ++j) {
                int c = ks * 32 + quad * 8 + j;
                float cv = ctx_sh[c * 17 + nlo] + ctx_sh[1088 + c * 17 + nlo];
                Bc.u[j] = f32_to_bf16_rne(cv);
            }
            bf16x8 ah = *(const bf16x8*)(woh + ks * 32);
            bf16x8 al = *(const bf16x8*)(wol + ks * 32);
            oacc = mfma_bf16(ah, Bc.v, oacc);
            oacc = mfma_bf16(al, Bc.v, oacc);
        }
        int t_g = t0 + nlo;
        if (t_g < TOUT) {
#pragma unroll
            for (int r = 0; r < 4; ++r) {
                int o = wave * 16 + quad * 4 + r;
                size_t off = ((size_t)b * COUT + o) * TOUT + t_g;
                out[off] = y[off] + oacc[r];
            }
        }
    }
}

// ---------------------------------------------------------------------------
extern "C" void kernel_launch(void* const* d_in, const int* in_sizes, int n_in,
                              void* d_out, int out_size, void* d_ws, size_t ws_size,
                              hipStream_t stream) {
    const float* x        = (const float*)d_in[0];
    const float* conv_w   = (const float*)d_in[1];
    const float* conv_b   = (const float*)d_in[2];
    const float* bn_gamma = (const float*)d_in[3];
    const float* bn_beta  = (const float*)d_in[4];
    const float* bn_mean  = (const float*)d_in[5];
    const float* bn_var   = (const float*)d_in[6];
    const float* wq       = (const float*)d_in[7];
    const float* wk       = (const float*)d_in[8];
    const float* wv       = (const float*)d_in[9];
    const float* wo       = (const float*)d_in[10];
    float* out = (float*)d_out;
    float* ws  = (float*)d_ws;

    // ws layout (float offsets)
    unsigned* sgn2        = (unsigned*)ws;                    // 6912 u32
    float* alpha          = ws + 110592;                      // 64
    float* scA            = ws + 110656;                      // 64
    float* scB            = ws + 110720;                      // 64
    unsigned short* w3_h  = (unsigned short*)(ws + 110848);   // 12288 us = 6144 f
    unsigned short* w3_l  = (unsigned short*)(ws + 116992);   // 12288 us -> 123136
    unsigned short* wo_h  = (unsigned short*)(ws + 123136);   // 2048 f
    unsigned short* wo_l  = (unsigned short*)(ws + 125184);   // 2048 f -> 127232
    float* yb             = ws + 131072;                      // 5,120,000
    unsigned short* q_h   = (unsigned short*)(ws + 5251072);  // 2,621,440 f
    unsigned short* k_h   = (unsigned short*)(ws + 7872512);  // 2,621,440 f
    unsigned short* vT_h  = (unsigned short*)(ws + 10493952); // ends 13,115,392 f

    hipLaunchKernelGGL(binarize_kernel, dim3(64), dim3(256), 0, stream, conv_w, sgn2, alpha);
    hipLaunchKernelGGL(transpose_w_kernel, dim3(5), dim3(256), 0, stream,
                       wq, wk, wv, wo, conv_b, bn_gamma, bn_beta, bn_mean, bn_var, alpha,
                       w3_h, w3_l, wo_h, wo_l, scA, scB);
    hipLaunchKernelGGL(conv_kernel, dim3(40, 128), dim3(256), 0, stream,
                       x, sgn2, scA, scB, w3_h, w3_l, yb, q_h, k_h, vT_h);
    hipLaunchKernelGGL(attn_kernel, dim3(40, 128), dim3(512), 0, stream,
                       q_h, k_h, vT_h, yb, wo_h, wo_l, out);
}

// Round 5
// 427.006 us; speedup vs baseline: 1.0271x; 1.0271x over previous
//
#include <hip/hip_runtime.h>
#include <math.h>

#define B_    128
#define CIN   128
#define TIN   2500
#define COUT  64
#define KW    27
#define TOUT  625
#define TPAD  640   // padded t extent for bf16 q/k/v planes
#define CTT   32    // conv t-tile
#define GROWS 152   // conv staging rows (span 4*31+27=151, pad to 152)

typedef __bf16 bf16x8 __attribute__((ext_vector_type(8)));
typedef float  f32x4  __attribute__((ext_vector_type(4)));
typedef float  f32x16 __attribute__((ext_vector_type(16)));

__device__ __forceinline__ unsigned short f32_to_bf16_rne(float v) {
    unsigned u = __float_as_uint(v);
    u += 0x7FFFu + ((u >> 16) & 1u);
    return (unsigned short)(u >> 16);
}

__device__ __forceinline__ f32x4 mfma_bf16(bf16x8 a, bf16x8 b, f32x4 c) {
    return __builtin_amdgcn_mfma_f32_16x16x32_bf16(a, b, c, 0, 0, 0);
}

// ---------------------------------------------------------------------------
// K0 (merged prep): blocks 0-63: sgn2 pack + alpha + scA/scB for o=blk
//   (alpha is block-local -> scA/scB computed here, no second kernel dep);
//   blocks 64-66: wq/wk/wv -> bf16 hi/lo planes [o][c]; block 67: wo hi/lo.
// ---------------------------------------------------------------------------
__global__ void prep_kernel(const float* __restrict__ w,
                            const float* __restrict__ wq, const float* __restrict__ wk,
                            const float* __restrict__ wv, const float* __restrict__ wo,
                            const float* __restrict__ conv_b, const float* __restrict__ gamma_,
                            const float* __restrict__ beta_, const float* __restrict__ mean_,
                            const float* __restrict__ var_,
                            unsigned* __restrict__ sgn2,
                            unsigned short* __restrict__ w3_h, unsigned short* __restrict__ w3_l,
                            unsigned short* __restrict__ wo_h, unsigned short* __restrict__ wo_l,
                            float* __restrict__ scA, float* __restrict__ scB) {
    int blk = blockIdx.x, tid = threadIdx.x;
    if (blk < 64) {
        __shared__ float red[256];
        const float* wrow = w + (size_t)blk * (CIN * KW);
        float s = 0.f;
        for (int idx = tid; idx < CIN * KW; idx += 256) s += fabsf(wrow[idx]);
        red[tid] = s;
        __syncthreads();
        for (int st = 128; st > 0; st >>= 1) {
            if (tid < st) red[tid] += red[tid + st];
            __syncthreads();
        }
        if (tid == 0) {
            float alpha = red[0] / (float)(CIN * KW);
            float inv = rsqrtf(var_[blk] + 1e-5f);
            float G = gamma_[blk] * inv;
            scA[blk] = alpha * G;
            scB[blk] = (conv_b[blk] - mean_[blk]) * G + beta_[blk];
        }
        for (int t = tid; t < KW * 4; t += 256) {
            int kk = t >> 2, kg = t & 3;
            unsigned u = 0;
#pragma unroll
            for (int cs = 0; cs < 4; cs++) {
#pragma unroll
                for (int j = 0; j < 8; j++) {
                    int c = cs * 32 + kg * 8 + j;
                    float v = wrow[c * KW + kk];
                    unsigned bit = (v > 0.f) ? 0u : 1u;
                    u |= bit << (cs * 8 + j);
                }
            }
            sgn2[(kk * 4 + kg) * 64 + blk] = u;
        }
    } else if (blk < 67) {
        const float* srcs[3] = {wq, wk, wv};
        const float* src = srcs[blk - 64];
        unsigned short* dh = w3_h + (size_t)(blk - 64) * 4096;
        unsigned short* dl = w3_l + (size_t)(blk - 64) * 4096;
        for (int idx = tid; idx < 4096; idx += 256) {
            float v = src[idx];
            unsigned short h = f32_to_bf16_rne(v);
            float hf = __uint_as_float((unsigned)h << 16);
            dh[idx] = h;
            dl[idx] = f32_to_bf16_rne(v - hf);
        }
    } else {
        for (int idx = tid; idx < 4096; idx += 256) {
            float v = wo[idx];
            unsigned short h = f32_to_bf16_rne(v);
            float hf = __uint_as_float((unsigned)h << 16);
            wo_h[idx] = h;
            wo_l[idx] = f32_to_bf16_rne(v - hf);
        }
    }
}

// ---------------------------------------------------------------------------
// K1: binarized conv1d + BN/ELU -> y, fused q/k/v projections.
//   This round: K-loop moved to 32x32x16 MFMA. One MFMA = 2x the MACs of
//   16x16x32 at the SAME 1KB LDS B-read -> B-traffic/MAC halved, MFMA count
//   halved (the kernel was LDS-issue bound: ~576 cyc/kk/block -> 384).
//   Waves = (o-half 32) x (c-half 64); c-half partials reconciled via an
//   8KB LDS overlay in dead xhi; epilogue + fused projections = proven R3
//   code verbatim (16x16 MFMA, o-slice 16 per wave).
// ---------------------------------------------------------------------------
__global__ __launch_bounds__(256, 4) void conv_kernel(
    const float* __restrict__ x, const unsigned* __restrict__ sgn2,
    const float* __restrict__ scA, const float* __restrict__ scB,
    const unsigned short* __restrict__ w3_h, const unsigned short* __restrict__ w3_l,
    float* __restrict__ y_out,
    unsigned short* __restrict__ q_h, unsigned short* __restrict__ k_h,
    unsigned short* __restrict__ vT_h)
{
    __shared__ __align__(16) unsigned short xhi[GROWS * 128];  // 38912 B
    __shared__ __align__(16) unsigned long long sgnlut[16];    // 128 B
    // overlays on xhi (valid only after the post-K-loop barrier):
    unsigned short* y_sh = xhi;            // [32][64] bf16, c8-swizzled
    unsigned short* s_sh = xhi + 2048;     // spike plane, same layout
    unsigned short* q_sh = xhi + 4096;     // [32][64] bf16, o8-swizzled
    unsigned short* k_sh = xhi + 6144;
    unsigned short* v_sh = xhi + 8192;     // [64][32] bf16, t8-swizzled
    float* part_sh = (float*)(xhi + 10240);  // 2048 f32 (c-half partials)

    int tid = threadIdx.x;
    // XCD-aware remap (2560 wgs, 2560%8==0 -> bijective)
    int id = blockIdx.x + 20 * blockIdx.y;
    int nid = (id & 7) * 320 + (id >> 3);
    int b = nid / 20;
    int t0 = (nid - b * 20) * CTT;

    // ---- nibble -> 4x bf16(+-1.0) LUT (bit=1 => -1.0) ----
    if (tid < 16) {
        unsigned long long e = 0;
#pragma unroll
        for (int j = 0; j < 4; ++j) {
            unsigned long long h = ((tid >> j) & 1) ? 0xBF80ull : 0x3F80ull;
            e |= h << (16 * j);
        }
        sgnlut[tid] = e;
    }

    // ---- stage x (hi bf16, RNE): task = (c8, gl); 8 loads -> one b128 ----
    const float* xb = x + (size_t)b * CIN * TIN;
    int gbase = 4 * t0 - 13;
    for (int task = tid; task < 16 * GROWS; task += 256) {
        int c8 = task / GROWS, gl = task - c8 * GROWS;
        int g = gbase + gl;
        bool valid = (gl < 151) && ((unsigned)g < (unsigned)TIN);
        float vs[8];
#pragma unroll
        for (int j = 0; j < 8; j++)
            vs[j] = valid ? xb[(size_t)(c8 * 8 + j) * TIN + g] : 0.f;
        union { unsigned u[4]; uint4 q; } H;
#pragma unroll
        for (int j = 0; j < 4; j++) {
            unsigned short h0 = f32_to_bf16_rne(vs[2 * j]);
            unsigned short h1 = f32_to_bf16_rne(vs[2 * j + 1]);
            H.u[j] = (unsigned)h0 | ((unsigned)h1 << 16);
        }
        int c8p = c8 ^ ((gl >> 2) & 15);
        *(uint4*)(xhi + gl * 128 + c8p * 8) = H.q;
    }
    __syncthreads();

    // ---- MFMA K-loop (32x32x16): wave = (oh = o-half, ch = c-half) ----
    int wave = tid >> 6, lane = tid & 63;
    int oh = wave & 1, ch = wave >> 1;
    int o0w = oh * 32;
    int lo = lane & 31;        // A: o-offset; B: t-offset
    int kg1 = lane >> 5;       // k-octet within K=16

    f32x16 acc = {0.f};
    const unsigned* sgb = sgn2 + o0w + lo;   // word [(kk*4+kgw)*64]
    unsigned w0 = sgb[kg1 * 64];
    unsigned w1 = sgb[(kg1 + 2) * 64];

#pragma unroll 1
    for (int kk = 0; kk < KW; ++kk) {
        unsigned n0 = 0, n1 = 0;
        if (kk < KW - 1) {
            n0 = sgb[((kk + 1) * 4 + kg1) * 64];
            n1 = sgb[((kk + 1) * 4 + kg1 + 2) * 64];
        }
        int gl = 4 * lo + kk;
        int rot = (gl >> 2) & 15;
        const unsigned short* xr = xhi + gl * 128;
#pragma unroll
        for (int ks = 0; ks < 4; ++ks) {
            int oct = ch * 8 + ks * 2 + kg1;
            int c8p = oct ^ rot;
            bf16x8 bx = *(const bf16x8*)(xr + c8p * 8);
            unsigned wsel = (ks & 1) ? w1 : w0;
            unsigned byte = (wsel >> (8 * (ch * 2 + (ks >> 1)))) & 0xFFu;
            union { unsigned long long u[2]; bf16x8 v; } A;
            A.u[0] = sgnlut[byte & 15u];
            A.u[1] = sgnlut[byte >> 4];
            acc = __builtin_amdgcn_mfma_f32_32x32x16_bf16(A.v, bx, acc, 0, 0, 0);
        }
        w0 = n0; w1 = n1;
    }
    __syncthreads();     // all waves done reading xhi -> overlays valid

    // ---- c-half reconcile: ch=1 publishes partials ----
    if (ch == 1) {
        float* p = part_sh + oh * 1024 + lane;
#pragma unroll
        for (int r = 0; r < 16; ++r) p[r * 64] = acc[r];
    }
    __syncthreads();

    // ---- ch=0: combine, BN/ELU, y_out store, pack y+spike (pads -> 0) ----
    if (ch == 0) {
        const float* p = part_sh + oh * 1024 + lane;
        int t_g = t0 + lo;
        bool tv = t_g < TOUT;
        // C 32x32 layout: col=lane&31 (t), row=(r&3)+8*(r>>2)+4*kg1 (o-off)
#pragma unroll
        for (int g2 = 0; g2 < 4; ++g2) {
            unsigned long long yp = 0, sp = 0;
#pragma unroll
            for (int j = 0; j < 4; ++j) {
                int r = g2 * 4 + j;
                float v = acc[r] + p[r * 64];
                int o = o0w + 4 * kg1 + 8 * g2 + j;
                float s = v * scA[o] + scB[o];
                float yv = s > 0.f ? s : expm1f(s);
                if (tv) {
                    y_out[((size_t)b * COUT + o) * TOUT + t_g] = yv;
                    yp |= (unsigned long long)f32_to_bf16_rne(yv) << (16 * j);
                    if (yv > 0.f) sp |= 0x3F80ull << (16 * j);
                }
            }
            int c8 = 4 * oh + g2;
            int idx = lo * 64 + ((c8 ^ (lo & 7)) << 3) + 4 * kg1;
            *(unsigned long long*)(y_sh + idx) = yp;
            *(unsigned long long*)(s_sh + idx) = sp;
        }
    }
    __syncthreads();

    // ---- fused projections (proven R3 code): wave -> o-slice 16 ----
    int quad = lane >> 4, col = lane & 15;
    int o0 = wave * 16;
    bf16x8 sf[2][2], yf[2][2];           // [tt][ks] B-fragments
#pragma unroll
    for (int tt = 0; tt < 2; ++tt)
#pragma unroll
        for (int ks = 0; ks < 2; ++ks) {
            int tl = tt * 16 + col;
            int idx = tl * 64 + (((ks * 4 + quad) ^ (tl & 7)) << 3);
            sf[tt][ks] = *(const bf16x8*)(s_sh + idx);
            yf[tt][ks] = *(const bf16x8*)(y_sh + idx);
        }
    size_t wofs = (size_t)(o0 + col) * 64 + quad * 8;
    f32x4 qa[2], ka[2], va[2];
#pragma unroll
    for (int tt = 0; tt < 2; ++tt) {
        qa[tt] = (f32x4){0.f, 0.f, 0.f, 0.f};
        ka[tt] = (f32x4){0.f, 0.f, 0.f, 0.f};
        va[tt] = (f32x4){0.f, 0.f, 0.f, 0.f};
    }
#pragma unroll
    for (int ks = 0; ks < 2; ++ks) {
        bf16x8 aqh = *(const bf16x8*)(w3_h + wofs + ks * 32);
        bf16x8 aql = *(const bf16x8*)(w3_l + wofs + ks * 32);
        bf16x8 akh = *(const bf16x8*)(w3_h + 4096 + wofs + ks * 32);
        bf16x8 akl = *(const bf16x8*)(w3_l + 4096 + wofs + ks * 32);
        bf16x8 avh = *(const bf16x8*)(w3_h + 8192 + wofs + ks * 32);
        bf16x8 avl = *(const bf16x8*)(w3_l + 8192 + wofs + ks * 32);
#pragma unroll
        for (int tt = 0; tt < 2; ++tt) {
            qa[tt] = mfma_bf16(aqh, sf[tt][ks], qa[tt]);
            qa[tt] = mfma_bf16(aql, sf[tt][ks], qa[tt]);
            ka[tt] = mfma_bf16(akh, sf[tt][ks], ka[tt]);
            ka[tt] = mfma_bf16(akl, sf[tt][ks], ka[tt]);
            va[tt] = mfma_bf16(avh, yf[tt][ks], va[tt]);
            va[tt] = mfma_bf16(avl, yf[tt][ks], va[tt]);
        }
    }
    // q/k -> LDS [t][o] (o8-swizzled, 8B packs); v -> v_sh [c][t] (t8-swz)
    int c8w = (o0 >> 3) + (quad >> 1);
    int cof = (quad & 1) * 4;
#pragma unroll
    for (int tt = 0; tt < 2; ++tt) {
        int tl = tt * 16 + col;
        int idx = tl * 64 + ((c8w ^ (tl & 7)) << 3) + cof;
        unsigned long long qp = 0, kp = 0;
#pragma unroll
        for (int r = 0; r < 4; ++r) {
            qp |= (unsigned long long)f32_to_bf16_rne(qa[tt][r]) << (16 * r);
            kp |= (unsigned long long)f32_to_bf16_rne(ka[tt][r]) << (16 * r);
        }
        *(unsigned long long*)(q_sh + idx) = qp;
        *(unsigned long long*)(k_sh + idx) = kp;
#pragma unroll
        for (int r = 0; r < 4; ++r) {
            int c = o0 + quad * 4 + r;
            int vidx = c * 32 + (((tt * 2 + (col >> 3)) ^ quad) << 3) + (col & 7);
            v_sh[vidx] = f32_to_bf16_rne(va[tt][r]);
        }
    }
    __syncthreads();

    // ---- cooperative coalesced stores ----
    {
        int tl = tid >> 3, seg = tid & 7;
        int idx = tl * 64 + ((seg ^ (tl & 7)) << 3);
        uint4 qv = *(const uint4*)(q_sh + idx);
        uint4 kv = *(const uint4*)(k_sh + idx);
        size_t go = ((size_t)b * TPAD + t0 + tl) * 64 + seg * 8;
        *(uint4*)(q_h + go) = qv;
        *(uint4*)(k_h + go) = kv;
        int c = tid >> 2, ts = tid & 3;
        int vidx = c * 32 + ((ts ^ ((c >> 2) & 3)) << 3);
        uint4 vv = *(const uint4*)(v_sh + vidx);
        *(uint4*)(vT_h + ((size_t)b * 64 + c) * TPAD + t0 + ts * 8) = vv;
    }
}

// ---------------------------------------------------------------------------
// K2: MFMA attention per (b, 16-t tile), 512 threads / 8 waves (unchanged).
// ---------------------------------------------------------------------------
__global__ __launch_bounds__(512, 3) void attn_kernel(
    const unsigned short* __restrict__ q_h, const unsigned short* __restrict__ k_h,
    const unsigned short* __restrict__ vT_h, const float* __restrict__ y,
    const unsigned short* __restrict__ wo_h, const unsigned short* __restrict__ wo_l,
    float* __restrict__ out)
{
    __shared__ __align__(16) float sc_sh[16 * 648];  // f32 scores, then bf16 P in place
    __shared__ float ctx_sh[2 * 64 * 17];
    __shared__ float rden[16];

    int tid = threadIdx.x;
    int id = blockIdx.x + 40 * blockIdx.y;
    int nid = (id & 7) * 640 + (id >> 3);
    int b = nid / 40;
    int t0 = (nid - b * 40) * 16;

    int wave = tid >> 6, lane = tid & 63;
    int quad = lane >> 4, nlo = lane & 15;

    // ---- scores: wave w covers s in [w*80, (w+1)*80), 5 nt steps ----
    const unsigned short* qb = q_h + ((size_t)b * TPAD + t0 + nlo) * 64 + quad * 8;
    bf16x8 qa0 = *(const bf16x8*)(qb);
    bf16x8 qa1 = *(const bf16x8*)(qb + 32);
    const unsigned short* kbase = k_h + (size_t)b * TPAD * 64 + quad * 8;
#pragma unroll 5
    for (int nt = 0; nt < 5; ++nt) {
        int s = wave * 80 + nt * 16 + nlo;
        const unsigned short* krow = kbase + (size_t)s * 64;
        bf16x8 kb0 = *(const bf16x8*)(krow);
        bf16x8 kb1 = *(const bf16x8*)(krow + 32);
        f32x4 acc = {0.f, 0.f, 0.f, 0.f};
        acc = mfma_bf16(qa0, kb0, acc);
        acc = mfma_bf16(qa1, kb1, acc);
#pragma unroll
        for (int r = 0; r < 4; ++r)
            sc_sh[(quad * 4 + r) * 648 + s] = acc[r] * 0.125f;
    }
    __syncthreads();

    // ---- softmax over s: 32 lanes/row, shfl reductions, in-place bf16 P ----
    int ti1 = tid >> 5, sg = tid & 31;
    float* srow = &sc_sh[ti1 * 648];
    float mx = -3.0e38f;
    for (int s = sg; s < TOUT; s += 32) mx = fmaxf(mx, srow[s]);
#pragma unroll
    for (int off = 16; off >= 1; off >>= 1) mx = fmaxf(mx, __shfl_xor(mx, off));

    unsigned short* prow = (unsigned short*)srow;
    float sum = 0.f;
#pragma unroll
    for (int k2 = 0; k2 < 10; ++k2) {
        int s = 2 * sg + 64 * k2;
        float2 v2 = *(const float2*)(srow + s);
        float e0 = (s     < TOUT) ? __expf(v2.x - mx) : 0.f;
        float e1 = (s + 1 < TOUT) ? __expf(v2.y - mx) : 0.f;
        sum += e0 + e1;
        unsigned u0 = __float_as_uint(e0); u0 += 0x7FFFu + ((u0 >> 16) & 1u);
        unsigned u1 = __float_as_uint(e1); u1 += 0x7FFFu + ((u1 >> 16) & 1u);
        *(unsigned*)(prow + s) = (u0 >> 16) | (u1 & 0xFFFF0000u);
    }
#pragma unroll
    for (int off = 16; off >= 1; off >>= 1) sum += __shfl_xor(sum, off);
    if (sg == 0) rden[ti1] = 1.f / sum;
    __syncthreads();

    // ---- PV: wave -> (c-tile = (w&3)*16, K-half = w>>2); 10 ks steps ----
    int cw = (wave & 3) * 16, kh = wave >> 2;
    const unsigned short* vb = vT_h + ((size_t)b * 64 + cw + nlo) * TPAD;
    const unsigned short* pb = (const unsigned short*)sc_sh + nlo * 1296;
    f32x4 cacc = {0.f, 0.f, 0.f, 0.f};
    int ks0 = kh * 10;
#pragma unroll 5
    for (int i = 0; i < 10; ++i) {
        int ks = ks0 + i;
        bf16x8 pv = *(const bf16x8*)(pb + ks * 32 + quad * 8);
        bf16x8 v8 = *(const bf16x8*)(vb + ks * 32 + quad * 8);
        cacc = mfma_bf16(pv, v8, cacc);
    }
#pragma unroll
    for (int r = 0; r < 4; ++r)
        ctx_sh[kh * 1088 + (cw + nlo) * 17 + quad * 4 + r] = cacc[r] * rden[quad * 4 + r];
    __syncthreads();

    // ---- epilogue (waves 0-3): out = y + wo @ ctx, wave -> o-tile ----
    if (wave < 4) {
        const unsigned short* woh = wo_h + (size_t)(wave * 16 + nlo) * 64 + quad * 8;
        const unsigned short* wol = wo_l + (size_t)(wave * 16 + nlo) * 64 + quad * 8;
        f32x4 oacc = {0.f, 0.f, 0.f, 0.f};
#pragma unroll
        for (int ks = 0; ks < 2; ++ks) {
            union { unsigned short u[8]; bf16x8 v; } Bc;
#pragma unroll
            for (int j = 0; j < 8; ++j) {
                int c = ks * 32 + quad * 8 + j;
                float cv = ctx_sh[c * 17 + nlo] + ctx_sh[1088 + c * 17 + nlo];
                Bc.u[j] = f32_to_bf16_rne(cv);
            }
            bf16x8 ah = *(const bf16x8*)(woh + ks * 32);
            bf16x8 al = *(const bf16x8*)(wol + ks * 32);
            oacc = mfma_bf16(ah, Bc.v, oacc);
            oacc = mfma_bf16(al, Bc.v, oacc);
        }
        int t_g = t0 + nlo;
        if (t_g < TOUT) {
#pragma unroll
            for (int r = 0; r < 4; ++r) {
                int o = wave * 16 + quad * 4 + r;
                size_t off = ((size_t)b * COUT + o) * TOUT + t_g;
                out[off] = y[off] + oacc[r];
            }
        }
    }
}

// ---------------------------------------------------------------------------
extern "C" void kernel_launch(void* const* d_in, const int* in_sizes, int n_in,
                              void* d_out, int out_size, void* d_ws, size_t ws_size,
                              hipStream_t stream) {
    const float* x        = (const float*)d_in[0];
    const float* conv_w   = (const float*)d_in[1];
    const float* conv_b   = (const float*)d_in[2];
    const float* bn_gamma = (const float*)d_in[3];
    const float* bn_beta  = (const float*)d_in[4];
    const float* bn_mean  = (const float*)d_in[5];
    const float* bn_var   = (const float*)d_in[6];
    const float* wq       = (const float*)d_in[7];
    const float* wk       = (const float*)d_in[8];
    const float* wv       = (const float*)d_in[9];
    const float* wo       = (const float*)d_in[10];
    float* out = (float*)d_out;
    float* ws  = (float*)d_ws;

    // ws layout (float offsets)
    unsigned* sgn2        = (unsigned*)ws;                    // 6912 u32
    float* scA            = ws + 110656;                      // 64
    float* scB            = ws + 110720;                      // 64
    unsigned short* w3_h  = (unsigned short*)(ws + 110848);   // 12288 us
    unsigned short* w3_l  = (unsigned short*)(ws + 116992);   // 12288 us
    unsigned short* wo_h  = (unsigned short*)(ws + 123136);   // 2048 f
    unsigned short* wo_l  = (unsigned short*)(ws + 125184);   // 2048 f
    float* yb             = ws + 131072;                      // 5,120,000
    unsigned short* q_h   = (unsigned short*)(ws + 5251072);
    unsigned short* k_h   = (unsigned short*)(ws + 7872512);
    unsigned short* vT_h  = (unsigned short*)(ws + 10493952);

    hipLaunchKernelGGL(prep_kernel, dim3(68), dim3(256), 0, stream,
                       conv_w, wq, wk, wv, wo, conv_b, bn_gamma, bn_beta, bn_mean, bn_var,
                       sgn2, w3_h, w3_l, wo_h, wo_l, scA, scB);
    hipLaunchKernelGGL(conv_kernel, dim3(20, 128), dim3(256), 0, stream,
                       x, sgn2, scA, scB, w3_h, w3_l, yb, q_h, k_h, vT_h);
    hipLaunchKernelGGL(attn_kernel, dim3(40, 128), dim3(512), 0, stream,
                       q_h, k_h, vT_h, yb, wo_h, wo_l, out);
}

// Round 6
// 425.847 us; speedup vs baseline: 1.0299x; 1.0027x over previous
//
#include <hip/hip_runtime.h>
#include <math.h>

#define B_    128
#define CIN   128
#define TIN   2500
#define COUT  64
#define KW    27
#define TOUT  625
#define TPAD  640   // padded t extent for bf16 q/k/v planes
#define CTT   32    // conv t-tile
#define GROWS 152   // conv staging rows (span 4*31+27=151, pad to 152)

typedef __bf16 bf16x8 __attribute__((ext_vector_type(8)));
typedef float  f32x4  __attribute__((ext_vector_type(4)));
typedef float  f32x16 __attribute__((ext_vector_type(16)));

__device__ __forceinline__ unsigned short f32_to_bf16_rne(float v) {
    unsigned u = __float_as_uint(v);
    u += 0x7FFFu + ((u >> 16) & 1u);
    return (unsigned short)(u >> 16);
}

__device__ __forceinline__ f32x4 mfma_bf16(bf16x8 a, bf16x8 b, f32x4 c) {
    return __builtin_amdgcn_mfma_f32_16x16x32_bf16(a, b, c, 0, 0, 0);
}

// ---------------------------------------------------------------------------
// K0 (merged prep): blocks 0-63: sgn2 pack + alpha + scA/scB for o=blk;
//   blocks 64-66: wq/wk/wv -> bf16 hi/lo planes [o][c]; block 67: wo hi/lo.
// ---------------------------------------------------------------------------
__global__ void prep_kernel(const float* __restrict__ w,
                            const float* __restrict__ wq, const float* __restrict__ wk,
                            const float* __restrict__ wv, const float* __restrict__ wo,
                            const float* __restrict__ conv_b, const float* __restrict__ gamma_,
                            const float* __restrict__ beta_, const float* __restrict__ mean_,
                            const float* __restrict__ var_,
                            unsigned* __restrict__ sgn2,
                            unsigned short* __restrict__ w3_h, unsigned short* __restrict__ w3_l,
                            unsigned short* __restrict__ wo_h, unsigned short* __restrict__ wo_l,
                            float* __restrict__ scA, float* __restrict__ scB) {
    int blk = blockIdx.x, tid = threadIdx.x;
    if (blk < 64) {
        __shared__ float red[256];
        const float* wrow = w + (size_t)blk * (CIN * KW);
        float s = 0.f;
        for (int idx = tid; idx < CIN * KW; idx += 256) s += fabsf(wrow[idx]);
        red[tid] = s;
        __syncthreads();
        for (int st = 128; st > 0; st >>= 1) {
            if (tid < st) red[tid] += red[tid + st];
            __syncthreads();
        }
        if (tid == 0) {
            float alpha = red[0] / (float)(CIN * KW);
            float inv = rsqrtf(var_[blk] + 1e-5f);
            float G = gamma_[blk] * inv;
            scA[blk] = alpha * G;
            scB[blk] = (conv_b[blk] - mean_[blk]) * G + beta_[blk];
        }
        for (int t = tid; t < KW * 4; t += 256) {
            int kk = t >> 2, kg = t & 3;
            unsigned u = 0;
#pragma unroll
            for (int cs = 0; cs < 4; cs++) {
#pragma unroll
                for (int j = 0; j < 8; j++) {
                    int c = cs * 32 + kg * 8 + j;
                    float v = wrow[c * KW + kk];
                    unsigned bit = (v > 0.f) ? 0u : 1u;
                    u |= bit << (cs * 8 + j);
                }
            }
            sgn2[(kk * 4 + kg) * 64 + blk] = u;
        }
    } else if (blk < 67) {
        const float* srcs[3] = {wq, wk, wv};
        const float* src = srcs[blk - 64];
        unsigned short* dh = w3_h + (size_t)(blk - 64) * 4096;
        unsigned short* dl = w3_l + (size_t)(blk - 64) * 4096;
        for (int idx = tid; idx < 4096; idx += 256) {
            float v = src[idx];
            unsigned short h = f32_to_bf16_rne(v);
            float hf = __uint_as_float((unsigned)h << 16);
            dh[idx] = h;
            dl[idx] = f32_to_bf16_rne(v - hf);
        }
    } else {
        for (int idx = tid; idx < 4096; idx += 256) {
            float v = wo[idx];
            unsigned short h = f32_to_bf16_rne(v);
            float hf = __uint_as_float((unsigned)h << 16);
            wo_h[idx] = h;
            wo_l[idx] = f32_to_bf16_rne(v - hf);
        }
    }
}

// ---------------------------------------------------------------------------
// K1: binarized conv1d + BN/ELU -> y, fused q/k/v projections (unchanged R5).
// ---------------------------------------------------------------------------
__global__ __launch_bounds__(256, 4) void conv_kernel(
    const float* __restrict__ x, const unsigned* __restrict__ sgn2,
    const float* __restrict__ scA, const float* __restrict__ scB,
    const unsigned short* __restrict__ w3_h, const unsigned short* __restrict__ w3_l,
    float* __restrict__ y_out,
    unsigned short* __restrict__ q_h, unsigned short* __restrict__ k_h,
    unsigned short* __restrict__ vT_h)
{
    __shared__ __align__(16) unsigned short xhi[GROWS * 128];  // 38912 B
    __shared__ __align__(16) unsigned long long sgnlut[16];    // 128 B
    // overlays on xhi (valid only after the post-K-loop barrier):
    unsigned short* y_sh = xhi;            // [32][64] bf16, c8-swizzled
    unsigned short* s_sh = xhi + 2048;     // spike plane, same layout
    unsigned short* q_sh = xhi + 4096;     // [32][64] bf16, o8-swizzled
    unsigned short* k_sh = xhi + 6144;
    unsigned short* v_sh = xhi + 8192;     // [64][32] bf16, t8-swizzled
    float* part_sh = (float*)(xhi + 10240);  // 2048 f32 (c-half partials)

    int tid = threadIdx.x;
    // XCD-aware remap (2560 wgs, 2560%8==0 -> bijective)
    int id = blockIdx.x + 20 * blockIdx.y;
    int nid = (id & 7) * 320 + (id >> 3);
    int b = nid / 20;
    int t0 = (nid - b * 20) * CTT;

    // ---- nibble -> 4x bf16(+-1.0) LUT (bit=1 => -1.0) ----
    if (tid < 16) {
        unsigned long long e = 0;
#pragma unroll
        for (int j = 0; j < 4; ++j) {
            unsigned long long h = ((tid >> j) & 1) ? 0xBF80ull : 0x3F80ull;
            e |= h << (16 * j);
        }
        sgnlut[tid] = e;
    }

    // ---- stage x (hi bf16, RNE): task = (c8, gl); 8 loads -> one b128 ----
    const float* xb = x + (size_t)b * CIN * TIN;
    int gbase = 4 * t0 - 13;
    for (int task = tid; task < 16 * GROWS; task += 256) {
        int c8 = task / GROWS, gl = task - c8 * GROWS;
        int g = gbase + gl;
        bool valid = (gl < 151) && ((unsigned)g < (unsigned)TIN);
        float vs[8];
#pragma unroll
        for (int j = 0; j < 8; j++)
            vs[j] = valid ? xb[(size_t)(c8 * 8 + j) * TIN + g] : 0.f;
        union { unsigned u[4]; uint4 q; } H;
#pragma unroll
        for (int j = 0; j < 4; j++) {
            unsigned short h0 = f32_to_bf16_rne(vs[2 * j]);
            unsigned short h1 = f32_to_bf16_rne(vs[2 * j + 1]);
            H.u[j] = (unsigned)h0 | ((unsigned)h1 << 16);
        }
        int c8p = c8 ^ ((gl >> 2) & 15);
        *(uint4*)(xhi + gl * 128 + c8p * 8) = H.q;
    }
    __syncthreads();

    // ---- MFMA K-loop (32x32x16): wave = (oh = o-half, ch = c-half) ----
    int wave = tid >> 6, lane = tid & 63;
    int oh = wave & 1, ch = wave >> 1;
    int o0w = oh * 32;
    int lo = lane & 31;        // A: o-offset; B: t-offset
    int kg1 = lane >> 5;       // k-octet within K=16

    f32x16 acc = {0.f};
    const unsigned* sgb = sgn2 + o0w + lo;   // word [(kk*4+kgw)*64]
    unsigned w0 = sgb[kg1 * 64];
    unsigned w1 = sgb[(kg1 + 2) * 64];

#pragma unroll 1
    for (int kk = 0; kk < KW; ++kk) {
        unsigned n0 = 0, n1 = 0;
        if (kk < KW - 1) {
            n0 = sgb[((kk + 1) * 4 + kg1) * 64];
            n1 = sgb[((kk + 1) * 4 + kg1 + 2) * 64];
        }
        int gl = 4 * lo + kk;
        int rot = (gl >> 2) & 15;
        const unsigned short* xr = xhi + gl * 128;
#pragma unroll
        for (int ks = 0; ks < 4; ++ks) {
            int oct = ch * 8 + ks * 2 + kg1;
            int c8p = oct ^ rot;
            bf16x8 bx = *(const bf16x8*)(xr + c8p * 8);
            unsigned wsel = (ks & 1) ? w1 : w0;
            unsigned byte = (wsel >> (8 * (ch * 2 + (ks >> 1)))) & 0xFFu;
            union { unsigned long long u[2]; bf16x8 v; } A;
            A.u[0] = sgnlut[byte & 15u];
            A.u[1] = sgnlut[byte >> 4];
            acc = __builtin_amdgcn_mfma_f32_32x32x16_bf16(A.v, bx, acc, 0, 0, 0);
        }
        w0 = n0; w1 = n1;
    }
    __syncthreads();     // all waves done reading xhi -> overlays valid

    // ---- c-half reconcile: ch=1 publishes partials ----
    if (ch == 1) {
        float* p = part_sh + oh * 1024 + lane;
#pragma unroll
        for (int r = 0; r < 16; ++r) p[r * 64] = acc[r];
    }
    __syncthreads();

    // ---- ch=0: combine, BN/ELU, y_out store, pack y+spike (pads -> 0) ----
    if (ch == 0) {
        const float* p = part_sh + oh * 1024 + lane;
        int t_g = t0 + lo;
        bool tv = t_g < TOUT;
#pragma unroll
        for (int g2 = 0; g2 < 4; ++g2) {
            unsigned long long yp = 0, sp = 0;
#pragma unroll
            for (int j = 0; j < 4; ++j) {
                int r = g2 * 4 + j;
                float v = acc[r] + p[r * 64];
                int o = o0w + 4 * kg1 + 8 * g2 + j;
                float s = v * scA[o] + scB[o];
                float yv = s > 0.f ? s : expm1f(s);
                if (tv) {
                    y_out[((size_t)b * COUT + o) * TOUT + t_g] = yv;
                    yp |= (unsigned long long)f32_to_bf16_rne(yv) << (16 * j);
                    if (yv > 0.f) sp |= 0x3F80ull << (16 * j);
                }
            }
            int c8 = 4 * oh + g2;
            int idx = lo * 64 + ((c8 ^ (lo & 7)) << 3) + 4 * kg1;
            *(unsigned long long*)(y_sh + idx) = yp;
            *(unsigned long long*)(s_sh + idx) = sp;
        }
    }
    __syncthreads();

    // ---- fused projections: wave -> o-slice 16 ----
    int quad = lane >> 4, col = lane & 15;
    int o0 = wave * 16;
    bf16x8 sf[2][2], yf[2][2];           // [tt][ks] B-fragments
#pragma unroll
    for (int tt = 0; tt < 2; ++tt)
#pragma unroll
        for (int ks = 0; ks < 2; ++ks) {
            int tl = tt * 16 + col;
            int idx = tl * 64 + (((ks * 4 + quad) ^ (tl & 7)) << 3);
            sf[tt][ks] = *(const bf16x8*)(s_sh + idx);
            yf[tt][ks] = *(const bf16x8*)(y_sh + idx);
        }
    size_t wofs = (size_t)(o0 + col) * 64 + quad * 8;
    f32x4 qa[2], ka[2], va[2];
#pragma unroll
    for (int tt = 0; tt < 2; ++tt) {
        qa[tt] = (f32x4){0.f, 0.f, 0.f, 0.f};
        ka[tt] = (f32x4){0.f, 0.f, 0.f, 0.f};
        va[tt] = (f32x4){0.f, 0.f, 0.f, 0.f};
    }
#pragma unroll
    for (int ks = 0; ks < 2; ++ks) {
        bf16x8 aqh = *(const bf16x8*)(w3_h + wofs + ks * 32);
        bf16x8 aql = *(const bf16x8*)(w3_l + wofs + ks * 32);
        bf16x8 akh = *(const bf16x8*)(w3_h + 4096 + wofs + ks * 32);
        bf16x8 akl = *(const bf16x8*)(w3_l + 4096 + wofs + ks * 32);
        bf16x8 avh = *(const bf16x8*)(w3_h + 8192 + wofs + ks * 32);
        bf16x8 avl = *(const bf16x8*)(w3_l + 8192 + wofs + ks * 32);
#pragma unroll
        for (int tt = 0; tt < 2; ++tt) {
            qa[tt] = mfma_bf16(aqh, sf[tt][ks], qa[tt]);
            qa[tt] = mfma_bf16(aql, sf[tt][ks], qa[tt]);
            ka[tt] = mfma_bf16(akh, sf[tt][ks], ka[tt]);
            ka[tt] = mfma_bf16(akl, sf[tt][ks], ka[tt]);
            va[tt] = mfma_bf16(avh, yf[tt][ks], va[tt]);
            va[tt] = mfma_bf16(avl, yf[tt][ks], va[tt]);
        }
    }
    // q/k -> LDS [t][o] (o8-swizzled, 8B packs); v -> v_sh [c][t] (t8-swz)
    int c8w = (o0 >> 3) + (quad >> 1);
    int cof = (quad & 1) * 4;
#pragma unroll
    for (int tt = 0; tt < 2; ++tt) {
        int tl = tt * 16 + col;
        int idx = tl * 64 + ((c8w ^ (tl & 7)) << 3) + cof;
        unsigned long long qp = 0, kp = 0;
#pragma unroll
        for (int r = 0; r < 4; ++r) {
            qp |= (unsigned long long)f32_to_bf16_rne(qa[tt][r]) << (16 * r);
            kp |= (unsigned long long)f32_to_bf16_rne(ka[tt][r]) << (16 * r);
        }
        *(unsigned long long*)(q_sh + idx) = qp;
        *(unsigned long long*)(k_sh + idx) = kp;
#pragma unroll
        for (int r = 0; r < 4; ++r) {
            int c = o0 + quad * 4 + r;
            int vidx = c * 32 + (((tt * 2 + (col >> 3)) ^ quad) << 3) + (col & 7);
            v_sh[vidx] = f32_to_bf16_rne(va[tt][r]);
        }
    }
    __syncthreads();

    // ---- cooperative coalesced stores ----
    {
        int tl = tid >> 3, seg = tid & 7;
        int idx = tl * 64 + ((seg ^ (tl & 7)) << 3);
        uint4 qv = *(const uint4*)(q_sh + idx);
        uint4 kv = *(const uint4*)(k_sh + idx);
        size_t go = ((size_t)b * TPAD + t0 + tl) * 64 + seg * 8;
        *(uint4*)(q_h + go) = qv;
        *(uint4*)(k_h + go) = kv;
        int c = tid >> 2, ts = tid & 3;
        int vidx = c * 32 + ((ts ^ ((c >> 2) & 3)) << 3);
        uint4 vv = *(const uint4*)(v_sh + vidx);
        *(uint4*)(vT_h + ((size_t)b * 64 + c) * TPAD + t0 + ts * 8) = vv;
    }
}

// ---------------------------------------------------------------------------
// K2: MFMA attention per (b, 16-t tile), 512 threads / 8 waves.
//   This round: scores stay in REGISTERS (20 f32/lane). Row max/sum via
//   4-round shfl_xor within 16-lane groups + 512B per-wave-partial LDS
//   buffers (broadcast float4 reads). LDS holds only bf16 P (16x648 halves,
//   20.7KB): written once post-exp, read once by PV as ds_read_b128.
//   LDS 50.2 -> 30.5KB => 4 blocks/CU (100% wave cap, was 75%).
// ---------------------------------------------------------------------------
__global__ __launch_bounds__(512, 8) void attn_kernel(
    const unsigned short* __restrict__ q_h, const unsigned short* __restrict__ k_h,
    const unsigned short* __restrict__ vT_h, const float* __restrict__ y,
    const unsigned short* __restrict__ wo_h, const unsigned short* __restrict__ wo_l,
    float* __restrict__ out)
{
    __shared__ __align__(16) unsigned short P_lds[16 * 648];  // 20736 B (bf16 P)
    __shared__ __align__(16) float pmax_sh[16 * 8];           // 512 B [t][wave]
    __shared__ __align__(16) float psum_sh[16 * 8];           // 512 B [t][wave]
    __shared__ float ctx_sh[2 * 64 * 17];                     // 8704 B => 30464 total

    int tid = threadIdx.x;
    int id = blockIdx.x + 40 * blockIdx.y;
    int nid = (id & 7) * 640 + (id >> 3);
    int b = nid / 40;
    int t0 = (nid - b * 40) * 16;

    int wave = tid >> 6, lane = tid & 63;
    int quad = lane >> 4, nlo = lane & 15;

    // ---- QK^T: wave w covers s in [w*80, (w+1)*80); scores stay in regs ----
    const unsigned short* qb = q_h + ((size_t)b * TPAD + t0 + nlo) * 64 + quad * 8;
    bf16x8 qa0 = *(const bf16x8*)(qb);
    bf16x8 qa1 = *(const bf16x8*)(qb + 32);
    const unsigned short* kbase = k_h + (size_t)b * TPAD * 64 + quad * 8;
    f32x4 acc[5];
#pragma unroll 5
    for (int nt = 0; nt < 5; ++nt) {
        int s = wave * 80 + nt * 16 + nlo;
        const unsigned short* krow = kbase + (size_t)s * 64;
        bf16x8 kb0 = *(const bf16x8*)(krow);
        bf16x8 kb1 = *(const bf16x8*)(krow + 32);
        f32x4 a = {0.f, 0.f, 0.f, 0.f};
        a = mfma_bf16(qa0, kb0, a);
        a = mfma_bf16(qa1, kb1, a);
        acc[nt] = a;
    }

    // ---- row max: lane-local over nt (masked), shfl over 16-lane group ----
    // C layout: lane (quad,nlo) holds rows t = quad*4+r, cols s = w*80+nt*16+nlo
    float rmx[4] = {-3.0e38f, -3.0e38f, -3.0e38f, -3.0e38f};
#pragma unroll
    for (int nt = 0; nt < 5; ++nt) {
        int s = wave * 80 + nt * 16 + nlo;
        bool v = s < TOUT;
#pragma unroll
        for (int r = 0; r < 4; ++r) {
            float sc = acc[nt][r] * 0.125f;
            acc[nt][r] = sc;                       // keep scaled score
            if (v) rmx[r] = fmaxf(rmx[r], sc);
        }
    }
#pragma unroll
    for (int off = 1; off < 16; off <<= 1)
#pragma unroll
        for (int r = 0; r < 4; ++r) rmx[r] = fmaxf(rmx[r], __shfl_xor(rmx[r], off));
    if (nlo == 0) {
#pragma unroll
        for (int r = 0; r < 4; ++r) pmax_sh[(quad * 4 + r) * 8 + wave] = rmx[r];
    }
    __syncthreads();

    // ---- final row max (broadcast float4 reads), exp in regs, partial sum ----
    float rsum[4] = {0.f, 0.f, 0.f, 0.f};
    float rowm[4];
#pragma unroll
    for (int r = 0; r < 4; ++r) {
        const float4* pm = (const float4*)&pmax_sh[(quad * 4 + r) * 8];
        float4 a = pm[0], c = pm[1];
        rowm[r] = fmaxf(fmaxf(fmaxf(a.x, a.y), fmaxf(a.z, a.w)),
                        fmaxf(fmaxf(c.x, c.y), fmaxf(c.z, c.w)));
    }
#pragma unroll
    for (int nt = 0; nt < 5; ++nt) {
        int s = wave * 80 + nt * 16 + nlo;
        bool v = s < TOUT;
#pragma unroll
        for (int r = 0; r < 4; ++r) {
            float e = v ? __expf(acc[nt][r] - rowm[r]) : 0.f;
            acc[nt][r] = e;
            rsum[r] += e;
        }
    }
#pragma unroll
    for (int off = 1; off < 16; off <<= 1)
#pragma unroll
        for (int r = 0; r < 4; ++r) rsum[r] += __shfl_xor(rsum[r], off);
    if (nlo == 0) {
#pragma unroll
        for (int r = 0; r < 4; ++r) psum_sh[(quad * 4 + r) * 8 + wave] = rsum[r];
    }

    // ---- store P bf16 into LDS [t][s], stride 648 halves ----
    unsigned short* pw = P_lds;
#pragma unroll
    for (int nt = 0; nt < 5; ++nt) {
        int s = wave * 80 + nt * 16 + nlo;
#pragma unroll
        for (int r = 0; r < 4; ++r)
            pw[(quad * 4 + r) * 648 + s] = f32_to_bf16_rne(acc[nt][r]);
    }
    __syncthreads();

    // ---- rden for this lane's rows (t = quad*4+r) ----
    float rden_r[4];
#pragma unroll
    for (int r = 0; r < 4; ++r) {
        const float4* ps = (const float4*)&psum_sh[(quad * 4 + r) * 8];
        float4 a = ps[0], c = ps[1];
        rden_r[r] = 1.f / (((a.x + a.y) + (a.z + a.w)) + ((c.x + c.y) + (c.z + c.w)));
    }

    // ---- PV: wave -> (c-tile = (w&3)*16, K-half = w>>2); 10 ks steps ----
    int cw = (wave & 3) * 16, kh = wave >> 2;
    const unsigned short* vb = vT_h + ((size_t)b * 64 + cw + nlo) * TPAD;
    const unsigned short* pb = P_lds + nlo * 648;   // P row t=nlo
    f32x4 cacc = {0.f, 0.f, 0.f, 0.f};
    int ks0 = kh * 10;
#pragma unroll 5
    for (int i = 0; i < 10; ++i) {
        int ks = ks0 + i;
        bf16x8 pv = *(const bf16x8*)(pb + ks * 32 + quad * 8);   // ds_read_b128
        bf16x8 v8 = *(const bf16x8*)(vb + ks * 32 + quad * 8);
        cacc = mfma_bf16(pv, v8, cacc);
    }
#pragma unroll
    for (int r = 0; r < 4; ++r)
        ctx_sh[kh * 1088 + (cw + nlo) * 17 + quad * 4 + r] = cacc[r] * rden_r[r];
    __syncthreads();

    // ---- epilogue (waves 0-3): out = y + wo @ ctx, wave -> o-tile ----
    if (wave < 4) {
        const unsigned short* woh = wo_h + (size_t)(wave * 16 + nlo) * 64 + quad * 8;
        const unsigned short* wol = wo_l + (size_t)(wave * 16 + nlo) * 64 + quad * 8;
        f32x4 oacc = {0.f, 0.f, 0.f, 0.f};
#pragma unroll
        for (int ks = 0; ks < 2; ++ks) {
            union { unsigned short u[8]; bf16x8 v; } Bc;
#pragma unroll
            for (int j = 0; j < 8; ++j) {
                int c = ks * 32 + quad * 8 + j;
                float cv = ctx_sh[c * 17 + nlo] + ctx_sh[1088 + c * 17 + nlo];
                Bc.u[j] = f32_to_bf16_rne(cv);
            }
            bf16x8 ah = *(const bf16x8*)(woh + ks * 32);
            bf16x8 al = *(const bf16x8*)(wol + ks * 32);
            oacc = mfma_bf16(ah, Bc.v, oacc);
            oacc = mfma_bf16(al, Bc.v, oacc);
        }
        int t_g = t0 + nlo;
        if (t_g < TOUT) {
#pragma unroll
            for (int r = 0; r < 4; ++r) {
                int o = wave * 16 + quad * 4 + r;
                size_t off = ((size_t)b * COUT + o) * TOUT + t_g;
                out[off] = y[off] + oacc[r];
            }
        }
    }
}

// ---------------------------------------------------------------------------
extern "C" void kernel_launch(void* const* d_in, const int* in_sizes, int n_in,
                              void* d_out, int out_size, void* d_ws, size_t ws_size,
                              hipStream_t stream) {
    const float* x        = (const float*)d_in[0];
    const float* conv_w   = (const float*)d_in[1];
    const float* conv_b   = (const float*)d_in[2];
    const float* bn_gamma = (const float*)d_in[3];
    const float* bn_beta  = (const float*)d_in[4];
    const float* bn_mean  = (const float*)d_in[5];
    const float* bn_var   = (const float*)d_in[6];
    const float* wq       = (const float*)d_in[7];
    const float* wk       = (const float*)d_in[8];
    const float* wv       = (const float*)d_in[9];
    const float* wo       = (const float*)d_in[10];
    float* out = (float*)d_out;
    float* ws  = (float*)d_ws;

    // ws layout (float offsets)
    unsigned* sgn2        = (unsigned*)ws;                    // 6912 u32
    float* scA            = ws + 110656;                      // 64
    float* scB            = ws + 110720;                      // 64
    unsigned short* w3_h  = (unsigned short*)(ws + 110848);   // 12288 us
    unsigned short* w3_l  = (unsigned short*)(ws + 116992);   // 12288 us
    unsigned short* wo_h  = (unsigned short*)(ws + 123136);   // 2048 f
    unsigned short* wo_l  = (unsigned short*)(ws + 125184);   // 2048 f
    float* yb             = ws + 131072;                      // 5,120,000
    unsigned short* q_h   = (unsigned short*)(ws + 5251072);
    unsigned short* k_h   = (unsigned short*)(ws + 7872512);
    unsigned short* vT_h  = (unsigned short*)(ws + 10493952);

    hipLaunchKernelGGL(prep_kernel, dim3(68), dim3(256), 0, stream,
                       conv_w, wq, wk, wv, wo, conv_b, bn_gamma, bn_beta, bn_mean, bn_var,
                       sgn2, w3_h, w3_l, wo_h, wo_l, scA, scB);
    hipLaunchKernelGGL(conv_kernel, dim3(20, 128), dim3(256), 0, stream,
                       x, sgn2, scA, scB, w3_h, w3_l, yb, q_h, k_h, vT_h);
    hipLaunchKernelGGL(attn_kernel, dim3(40, 128), dim3(512), 0, stream,
                       q_h, k_h, vT_h, yb, wo_h, wo_l, out);
}